// Round 19
// baseline (160.982 us; speedup 1.0000x reference)
//
#include <hip/hip_runtime.h>
#include <math.h>

#define NN 65536
#define NE 1048576
#define CAP 17408   // per-bucket ebin capacity (mean 16384 + 8-sigma)
#define PCAP 24576  // per-bucket padded pack capacity

typedef __attribute__((ext_vector_type(8))) short short8;
typedef __attribute__((ext_vector_type(4))) float f32x4;

__device__ inline unsigned short f2bf(float f) {
  unsigned u = __float_as_uint(f);
  unsigned r = u + 0x7fff + ((u >> 16) & 1);  // RNE
  return (unsigned short)(r >> 16);
}
__device__ inline float bf2f(unsigned short h) { return __uint_as_float(((unsigned)h) << 16); }

// batch of 8 edges: vals + 16B h-row chunks (all statically indexed -> registers)
struct HB {
  float v[8];
  uint4 h[8];
};
__device__ __forceinline__ void load_hb(const int2* __restrict__ pack, int off, const char* __restrict__ hb,
                                        unsigned fo, HB& B) {
  int4 p0 = *(const int4*)&pack[off];
  int4 p1 = *(const int4*)&pack[off + 2];
  int4 p2 = *(const int4*)&pack[off + 4];
  int4 p3 = *(const int4*)&pack[off + 6];
  int sx[8] = {p0.x, p0.z, p1.x, p1.z, p2.x, p2.z, p3.x, p3.z};
  int vv[8] = {p0.y, p0.w, p1.y, p1.w, p2.y, p2.w, p3.y, p3.w};
#pragma unroll
  for (int u = 0; u < 8; ++u) {
    B.v[u] = __int_as_float(vv[u]);
    B.h[u] = *(const uint4*)(hb + ((unsigned)sx[u] + fo));
  }
}
__device__ __forceinline__ void fma_hb(const HB& B, float* c) {
#pragma unroll
  for (int u = 0; u < 8; ++u) {
    float v = B.v[u];
    c[0] = fmaf(v, __uint_as_float(B.h[u].x << 16), c[0]);
    c[1] = fmaf(v, __uint_as_float(B.h[u].x & 0xffff0000u), c[1]);
    c[2] = fmaf(v, __uint_as_float(B.h[u].y << 16), c[2]);
    c[3] = fmaf(v, __uint_as_float(B.h[u].y & 0xffff0000u), c[3]);
    c[4] = fmaf(v, __uint_as_float(B.h[u].z << 16), c[4]);
    c[5] = fmaf(v, __uint_as_float(B.h[u].z & 0xffff0000u), c[5]);
    c[6] = fmaf(v, __uint_as_float(B.h[u].w << 16), c[6]);
    c[7] = fmaf(v, __uint_as_float(B.h[u].w & 0xffff0000u), c[7]);
  }
}
// pipelined gather-accumulate over a padded edge list (rounds of 8)
__device__ __forceinline__ void agg_pipe(const int2* __restrict__ pack, int i0, int pdeg,
                                         const char* __restrict__ hb, unsigned fo, float* c) {
  if (pdeg <= 0) return;
  HB A, B;
  load_hb(pack, i0, hb, fo, A);
  int rounds = pdeg >> 3;
  int r = 1;
  for (; r + 1 < rounds; r += 2) {
    load_hb(pack, i0 + (r << 3), hb, fo, B);
    fma_hb(A, c);
    load_hb(pack, i0 + ((r + 1) << 3), hb, fo, A);
    fma_hb(B, c);
  }
  if (r < rounds) {
    load_hb(pack, i0 + (r << 3), hb, fo, B);
    fma_hb(A, c);
    fma_hb(B, c);
  } else {
    fma_hb(A, c);
  }
}

// ---------------- merged prep: x packing + gcur zero + W3 split-bf16 frags + gf zero ----------
__global__ __launch_bounds__(256) void k_prep(const float* __restrict__ x, float4* __restrict__ x4,
                                              int* __restrict__ gcur, const float* __restrict__ w3,
                                              unsigned short* __restrict__ bfrag, unsigned* __restrict__ gf) {
  int bid = blockIdx.x, tid = threadIdx.x;
  if (bid < 256) {
    if (bid == 0 && tid < 64) gcur[tid] = 0;
    int n = bid * 256 + tid;
    x4[n] = make_float4(x[3 * n], x[3 * n + 1], x[3 * n + 2], 0.f);
  } else {
    int t = (bid - 256) * 256 + tid;  // 0..131071
    if (t < 65536) gf[t] = 0u;
    int e = t & 7, g = (t >> 3) & 3, col = (t >> 5) & 1023, q = t >> 15;
    int k = (q & 1) * 32 + g * 8 + e;
    float v = w3[k * 1024 + col];
    unsigned short hv = f2bf(v);
    bfrag[t] = (q < 2) ? hv : f2bf(v - bf2f(hv));
  }
}

// ---------------- CSR build, pass 1: bin edges by shape (dst>>10), vectorized reads ----------
__global__ __launch_bounds__(256) void k_bin(const int* __restrict__ src, const int* __restrict__ dst,
                                             const float* __restrict__ val, int* __restrict__ gcur,
                                             uint2* __restrict__ ebin) {
  __shared__ int cnt[64], base[64];
  int tid = threadIdx.x;
  if (tid < 64) cnt[tid] = 0;
  __syncthreads();
  int e0 = blockIdx.x * 4096;
  const int4* src4 = (const int4*)(src + e0);
  const int4* dst4 = (const int4*)(dst + e0);
  const float4* val4 = (const float4*)(val + e0);
  int rsrc[16], rdst[16], rrank[16];
  float rval[16];
#pragma unroll
  for (int i = 0; i < 4; ++i) {
    int4 s4 = src4[i * 256 + tid];
    int4 d4 = dst4[i * 256 + tid];
    float4 v4 = val4[i * 256 + tid];
    rsrc[4 * i + 0] = s4.x; rsrc[4 * i + 1] = s4.y; rsrc[4 * i + 2] = s4.z; rsrc[4 * i + 3] = s4.w;
    rdst[4 * i + 0] = d4.x; rdst[4 * i + 1] = d4.y; rdst[4 * i + 2] = d4.z; rdst[4 * i + 3] = d4.w;
    rval[4 * i + 0] = v4.x; rval[4 * i + 1] = v4.y; rval[4 * i + 2] = v4.z; rval[4 * i + 3] = v4.w;
#pragma unroll
    for (int u = 0; u < 4; ++u) rrank[4 * i + u] = atomicAdd(&cnt[rdst[4 * i + u] >> 10], 1);
  }
  __syncthreads();
  if (tid < 64) base[tid] = atomicAdd(&gcur[tid], cnt[tid]);
  __syncthreads();
#pragma unroll
  for (int i = 0; i < 16; ++i) {
    int b = rdst[i] >> 10;
    ebin[b * CAP + base[b] + rrank[i]] =
        make_uint2((unsigned)rsrc[i] | ((unsigned)(rdst[i] & 1023) << 16), (unsigned)__float_as_int(rval[i]));
  }
}

// ---------------- CSR build, pass 2: register-cached single-read, wave-shfl scan -------------
__global__ __launch_bounds__(1024) void k_csr(const int* __restrict__ gcnt, const uint2* __restrict__ ebin,
                                              int2* __restrict__ offdeg, int2* __restrict__ pack) {
  __shared__ int lcnt[1024], lcur[1024];
  __shared__ int wsum[16], woff[16];
  int b = blockIdx.x, tid = threadIdx.x;
  int count = gcnt[b];
  int gbase = b * PCAP;
  lcnt[tid] = 0;
  __syncthreads();
  const uint2* eb = ebin + (size_t)b * CAP;
  // single read of this thread's <=20 entries into registers (statically indexed)
  uint2 es[5][4];
#pragma unroll
  for (int i0 = 0; i0 < 5; ++i0)
#pragma unroll
    for (int u = 0; u < 4; ++u) {
      int i = i0 * 4096 + u * 1024 + tid;
      es[i0][u] = eb[min(i, count - 1)];
    }
  // histogram
#pragma unroll
  for (int i0 = 0; i0 < 5; ++i0)
#pragma unroll
    for (int u = 0; u < 4; ++u) {
      int i = i0 * 4096 + u * 1024 + tid;
      if (i < count) atomicAdd(&lcnt[(es[i0][u].x >> 16) & 1023], 1);
    }
  __syncthreads();
  int deg = lcnt[tid];
  int pdeg = (deg + 7) & ~7;
  int lane = tid & 63, wid = tid >> 6;
  int v = pdeg;
#pragma unroll
  for (int d = 1; d < 64; d <<= 1) {
    int t = __shfl_up(v, d);
    if (lane >= d) v += t;
  }
  if (lane == 63) wsum[wid] = v;
  __syncthreads();
  if (tid < 16) {
    int s = wsum[tid];
    int sv = s;
#pragma unroll
    for (int d = 1; d < 16; d <<= 1) {
      int t = __shfl_up(sv, d);
      if (tid >= d) sv += t;
    }
    woff[tid] = sv - s;
  }
  __syncthreads();
  int o0 = woff[wid] + v - pdeg;  // exclusive padded prefix
  lcur[tid] = o0;
  offdeg[b * 1024 + tid] = make_int2(gbase + o0, pdeg);
  __syncthreads();
  // placement from registers
#pragma unroll
  for (int i0 = 0; i0 < 5; ++i0)
#pragma unroll
    for (int u = 0; u < 4; ++u) {
      int i = i0 * 4096 + u * 1024 + tid;
      if (i < count) {
        int ld = (es[i0][u].x >> 16) & 1023;
        int p = atomicAdd(&lcur[ld], 1);
        pack[gbase + p] = make_int2((int)((es[i0][u].x & 0xffffu) << 7), (int)es[i0][u].y);
      }
    }
  int pend = o0 + pdeg;
  for (int p = o0 + deg; p < pend; ++p) pack[gbase + p] = make_int2(0, 0);
}

// ---------------- fused layer-1: agg(x) -> @W1+b1, relu -> h1 bf16 (pipelined gathers) -------
__global__ __launch_bounds__(256) void k_agg1(const int2* __restrict__ offdeg, const int2* __restrict__ pack,
                                              const float4* __restrict__ x4, const float* __restrict__ w,
                                              const float* __restrict__ b, unsigned short* __restrict__ out) {
  __shared__ float sw[256];
  __shared__ float sa[256][4];
  int tid = threadIdx.x;
  sw[tid] = (tid < 192) ? w[tid] : b[tid - 192];
  int n = blockIdx.x * 256 + tid;
  int2 od = offdeg[n];
  int i0 = od.x, pdeg = od.y;
  float a0 = 0.f, a1 = 0.f, a2 = 0.f;

  struct XB { float v[8]; float4 q[8]; };
  auto loadx = [&](int off, XB& B) {
    int4 p0 = *(const int4*)&pack[off];
    int4 p1 = *(const int4*)&pack[off + 2];
    int4 p2 = *(const int4*)&pack[off + 4];
    int4 p3 = *(const int4*)&pack[off + 6];
    int sx[8] = {p0.x, p0.z, p1.x, p1.z, p2.x, p2.z, p3.x, p3.z};
    int vv[8] = {p0.y, p0.w, p1.y, p1.w, p2.y, p2.w, p3.y, p3.w};
#pragma unroll
    for (int u = 0; u < 8; ++u) {
      B.v[u] = __int_as_float(vv[u]);
      B.q[u] = x4[(unsigned)sx[u] >> 7];
    }
  };
  auto fmax_ = [&](const XB& B) {
#pragma unroll
    for (int u = 0; u < 8; ++u) {
      a0 = fmaf(B.v[u], B.q[u].x, a0);
      a1 = fmaf(B.v[u], B.q[u].y, a1);
      a2 = fmaf(B.v[u], B.q[u].z, a2);
    }
  };
  if (pdeg > 0) {
    XB A, B;
    loadx(i0, A);
    int rounds = pdeg >> 3;
    int r = 1;
    for (; r + 1 < rounds; r += 2) {
      loadx(i0 + (r << 3), B);
      fmax_(A);
      loadx(i0 + ((r + 1) << 3), A);
      fmax_(B);
    }
    if (r < rounds) {
      loadx(i0 + (r << 3), B);
      fmax_(A);
      fmax_(B);
    } else {
      fmax_(A);
    }
  }
  sa[tid][0] = a0; sa[tid][1] = a1; sa[tid][2] = a2;
  __syncthreads();
  int j = tid & 63, g = tid >> 6;
  float wj0 = sw[j], wj1 = sw[64 + j], wj2 = sw[128 + j], bj = sw[192 + j];
  int nb = blockIdx.x * 256 + g * 64;
  for (int r = 0; r < 64; ++r) {
    float r0 = fmaf(sa[g * 64 + r][0], wj0, bj);
    r0 = fmaf(sa[g * 64 + r][1], wj1, r0);
    r0 = fmaf(sa[g * 64 + r][2], wj2, r0);
    out[(size_t)(nb + r) * 64 + j] = f2bf(fmaxf(r0, 0.f));
  }
}

// ---------------- fused layer-2: agg(h1) -> @W2+b2, relu -> h2 bf16 (pipelined) --------------
__global__ __launch_bounds__(256) void k_agg64g2(const int2* __restrict__ offdeg, const int2* __restrict__ pack,
                                                 const unsigned short* __restrict__ h,
                                                 const float* __restrict__ w2, const float* __restrict__ b2,
                                                 unsigned short* __restrict__ out) {
  __shared__ float sw[64][64];    // sw[k][j]
  __shared__ float rows[32][64];
  int tid = threadIdx.x;
  int lane = tid & 63, wv = tid >> 6;
  for (int t = tid; t < 1024; t += 256) ((float4*)sw)[t] = ((const float4*)w2)[t];
  __syncthreads();
  int o = lane >> 3, fl = lane & 7;  // node octant, feat group (feats 8fl..8fl+7)
  int n = blockIdx.x * 32 + wv * 8 + o;
  int2 od = offdeg[n];
  float c[8] = {0.f, 0.f, 0.f, 0.f, 0.f, 0.f, 0.f, 0.f};
  agg_pipe(pack, od.x, od.y, (const char*)h, (unsigned)(fl << 4), c);
  ((float4*)rows[wv * 8 + o])[fl * 2 + 0] = make_float4(c[0], c[1], c[2], c[3]);
  ((float4*)rows[wv * 8 + o])[fl * 2 + 1] = make_float4(c[4], c[5], c[6], c[7]);
  int nA = blockIdx.x * 32 + wv * 8;
  float bb = b2[lane];
  float acc[8];
#pragma unroll
  for (int r = 0; r < 8; ++r) acc[r] = bb;
#pragma unroll
  for (int kk = 0; kk < 16; ++kk) {
    float w0 = sw[4 * kk + 0][lane], w1 = sw[4 * kk + 1][lane];
    float w2v = sw[4 * kk + 2][lane], w3v = sw[4 * kk + 3][lane];
#pragma unroll
    for (int r = 0; r < 8; ++r) {
      float4 qr = ((const float4*)rows[wv * 8 + r])[kk];
      acc[r] = fmaf(qr.x, w0, acc[r]);
      acc[r] = fmaf(qr.y, w1, acc[r]);
      acc[r] = fmaf(qr.z, w2v, acc[r]);
      acc[r] = fmaf(qr.w, w3v, acc[r]);
    }
  }
#pragma unroll
  for (int r = 0; r < 8; ++r)
    out[(size_t)(nA + r) * 64 + lane] = f2bf(fmaxf(acc[r], 0.f));
}

// 64-feature aggregation -> split-bf16 planes; pipelined gathers
__global__ __launch_bounds__(256) void k_agg64_split(const int2* __restrict__ offdeg, const int2* __restrict__ pack,
                                                     const unsigned short* __restrict__ h,
                                                     unsigned short* __restrict__ hi,
                                                     unsigned short* __restrict__ lo) {
  int tid = threadIdx.x;
  int lane = tid & 63, wv = tid >> 6;
  int o = lane >> 3, fl = lane & 7;
  int n = blockIdx.x * 32 + wv * 8 + o;
  int2 od = offdeg[n];
  float c[8] = {0.f, 0.f, 0.f, 0.f, 0.f, 0.f, 0.f, 0.f};
  agg_pipe(pack, od.x, od.y, (const char*)h, (unsigned)(fl << 4), c);
  unsigned short h0 = f2bf(c[0]), h1 = f2bf(c[1]), h2 = f2bf(c[2]), h3 = f2bf(c[3]);
  unsigned short h4 = f2bf(c[4]), h5 = f2bf(c[5]), h6 = f2bf(c[6]), h7 = f2bf(c[7]);
  uint4 hiw = make_uint4((unsigned)h0 | ((unsigned)h1 << 16), (unsigned)h2 | ((unsigned)h3 << 16),
                         (unsigned)h4 | ((unsigned)h5 << 16), (unsigned)h6 | ((unsigned)h7 << 16));
  unsigned short l0 = f2bf(c[0] - bf2f(h0)), l1 = f2bf(c[1] - bf2f(h1));
  unsigned short l2 = f2bf(c[2] - bf2f(h2)), l3 = f2bf(c[3] - bf2f(h3));
  unsigned short l4 = f2bf(c[4] - bf2f(h4)), l5 = f2bf(c[5] - bf2f(h5));
  unsigned short l6 = f2bf(c[6] - bf2f(h6)), l7 = f2bf(c[7] - bf2f(h7));
  uint4 low = make_uint4((unsigned)l0 | ((unsigned)l1 << 16), (unsigned)l2 | ((unsigned)l3 << 16),
                         (unsigned)l4 | ((unsigned)l5 << 16), (unsigned)l6 | ((unsigned)l7 << 16));
  ((uint4*)hi)[(size_t)n * 8 + fl] = hiw;
  ((uint4*)lo)[(size_t)n * 8 + fl] = low;
}

// ---------------- GCN layer 3 GEMM + maxpool via MFMA (split-bf16) ----------------
__global__ __launch_bounds__(512) void k_gemm3max(const unsigned short* __restrict__ Ahi,
                                                  const unsigned short* __restrict__ Alo,
                                                  const unsigned short* __restrict__ Bfrag,
                                                  const float* __restrict__ b3,
                                                  unsigned* __restrict__ gf) {
  int b = blockIdx.x;
  int colhalf = b & 1, rowchunk = b >> 1;
  int shape = rowchunk >> 2;
  int tid = threadIdx.x;
  int wv = tid >> 6, l = tid & 63;
  int g = l >> 4, lr = l & 15;

  const short8* bf = (const short8*)Bfrag;
  int c0 = colhalf * 512 + wv * 64 + lr;
  short8 B0[4], B1[4], B2[4], B3[4];
#pragma unroll
  for (int ct = 0; ct < 4; ++ct) {
    int col = c0 + ct * 16;
    B0[ct] = bf[(0 * 1024 + col) * 4 + g];
    B1[ct] = bf[(1 * 1024 + col) * 4 + g];
    B2[ct] = bf[(2 * 1024 + col) * 4 + g];
    B3[ct] = bf[(3 * 1024 + col) * 4 + g];
  }

  float m[4] = {-1e30f, -1e30f, -1e30f, -1e30f};
  size_t abase = ((size_t)rowchunk * 256 + lr) * 64 + g * 8;
  for (int t = 0; t < 16; ++t) {
    size_t o = abase + (size_t)t * 16 * 64;
    short8 ah0 = *(const short8*)(Ahi + o);
    short8 ah1 = *(const short8*)(Ahi + o + 32);
    short8 al0 = *(const short8*)(Alo + o);
    short8 al1 = *(const short8*)(Alo + o + 32);
#pragma unroll
    for (int ct = 0; ct < 4; ++ct) {
      f32x4 acc = {0.f, 0.f, 0.f, 0.f};
      acc = __builtin_amdgcn_mfma_f32_16x16x32_bf16(ah0, B0[ct], acc, 0, 0, 0);
      acc = __builtin_amdgcn_mfma_f32_16x16x32_bf16(ah1, B1[ct], acc, 0, 0, 0);
      acc = __builtin_amdgcn_mfma_f32_16x16x32_bf16(ah0, B2[ct], acc, 0, 0, 0);
      acc = __builtin_amdgcn_mfma_f32_16x16x32_bf16(ah1, B3[ct], acc, 0, 0, 0);
      acc = __builtin_amdgcn_mfma_f32_16x16x32_bf16(al0, B0[ct], acc, 0, 0, 0);
      acc = __builtin_amdgcn_mfma_f32_16x16x32_bf16(al1, B1[ct], acc, 0, 0, 0);
      m[ct] = fmaxf(m[ct], fmaxf(fmaxf(acc[0], acc[1]), fmaxf(acc[2], acc[3])));
    }
  }
#pragma unroll
  for (int ct = 0; ct < 4; ++ct) {
    float mm = m[ct];
    mm = fmaxf(mm, __shfl_xor(mm, 16));
    mm = fmaxf(mm, __shfl_xor(mm, 32));
    if (g == 0) {
      int col = c0 + ct * 16;
      float v = fmaxf(mm + b3[col], 0.f);
      atomicMax(&gf[shape * 1024 + col], __float_as_uint(v));
    }
  }
}

// ---------------- MLP head ----------------
__global__ __launch_bounds__(512) void k_fc(const float* __restrict__ in, const float* __restrict__ w,
                                            const float* __restrict__ bias, float* __restrict__ out,
                                            int K, int J) {
  __shared__ float sin_[1024];
  __shared__ float part[8][64];
  int jt = blockIdx.x, bb = blockIdx.y;
  int tid = threadIdx.x, s = tid >> 6, lane = tid & 63;
  for (int i = tid; i < K; i += 512) sin_[i] = in[bb * K + i];
  __syncthreads();
  int j = (jt << 6) + lane;
  int Ks = K >> 3;
  int k0 = s * Ks;
  float acc = 0.f;
  for (int k = 0; k < Ks; k += 16) {
    float wv[16];
#pragma unroll
    for (int u = 0; u < 16; ++u) wv[u] = w[(k0 + k + u) * J + j];
#pragma unroll
    for (int u = 0; u < 16; ++u) acc = fmaf(sin_[k0 + k + u], wv[u], acc);
  }
  part[s][lane] = acc;
  __syncthreads();
  if (tid < 64) {
    float r = bias[(jt << 6) + tid];
#pragma unroll
    for (int u = 0; u < 8; ++u) r += part[u][tid];
    out[bb * J + (jt << 6) + tid] = r;
  }
}

// fused BN1 + relu + fc2: grid (4, 64) = (jt, row); each block recomputes column stats
__global__ __launch_bounds__(512) void k_fc2n(const float* __restrict__ z1, const float* __restrict__ g1,
                                              const float* __restrict__ be1, const float* __restrict__ w,
                                              const float* __restrict__ bias, float* __restrict__ out) {
  __shared__ float szn[512];
  __shared__ float part[8][64];
  int jt = blockIdx.x, row = blockIdx.y;
  int tid = threadIdx.x;
  // BN stats for column tid (two-pass, matches reference biased var)
  {
    float s = 0.f;
#pragma unroll 8
    for (int r = 0; r < 64; ++r) s += z1[r * 512 + tid];
    float mean = s * (1.f / 64.f);
    float v = 0.f;
#pragma unroll 8
    for (int r = 0; r < 64; ++r) {
      float d = z1[r * 512 + tid] - mean;
      v = fmaf(d, d, v);
    }
    float scale = g1[tid] / sqrtf(v * (1.f / 64.f) + 1e-5f);
    float shift = be1[tid] - mean * scale;
    szn[tid] = fmaxf(fmaf(z1[row * 512 + tid], scale, shift), 0.f);
  }
  __syncthreads();
  int s8 = tid >> 6, lane = tid & 63;
  int j = (jt << 6) + lane;
  int k0 = s8 * 64;
  float acc = 0.f;
  for (int k = 0; k < 64; k += 16) {
    float wv[16];
#pragma unroll
    for (int u = 0; u < 16; ++u) wv[u] = w[(k0 + k + u) * 256 + j];
#pragma unroll
    for (int u = 0; u < 16; ++u) acc = fmaf(szn[k0 + k + u], wv[u], acc);
  }
  part[s8][lane] = acc;
  __syncthreads();
  if (tid < 64) {
    float r = bias[(jt << 6) + tid];
#pragma unroll
    for (int u = 0; u < 8; ++u) r += part[u][tid];
    out[row * 256 + (jt << 6) + tid] = r;
  }
}

// fused BN2 + relu + fc3 + log_softmax: grid 64 (one block per batch row)
__global__ __launch_bounds__(256) void k_head2(const float* __restrict__ z2, const float* __restrict__ g,
                                               const float* __restrict__ bt, const float* __restrict__ w,
                                               const float* __restrict__ b, float* __restrict__ out) {
  __shared__ float sz[256];
  __shared__ float part[4][64];
  int bb = blockIdx.x, j = threadIdx.x;
  float s = 0.f;
#pragma unroll 8
  for (int r = 0; r < 64; ++r) s += z2[r * 256 + j];
  float mean = s * (1.f / 64.f);
  float v = 0.f;
#pragma unroll 8
  for (int r = 0; r < 64; ++r) {
    float d = z2[r * 256 + j] - mean;
    v = fmaf(d, d, v);
  }
  float scale = g[j] / sqrtf(v * (1.f / 64.f) + 1e-5f);
  float shift = bt[j] - mean * scale;
  sz[j] = fmaxf(fmaf(z2[bb * 256 + j], scale, shift), 0.f);
  __syncthreads();
  int sgrp = j >> 6, lane = j & 63;
  float acc = 0.f;
  if (lane < 40) {
#pragma unroll
    for (int k = 0; k < 64; k += 4) {
      int kk = sgrp * 64 + k;
      acc = fmaf(sz[kk + 0], w[(kk + 0) * 40 + lane], acc);
      acc = fmaf(sz[kk + 1], w[(kk + 1) * 40 + lane], acc);
      acc = fmaf(sz[kk + 2], w[(kk + 2) * 40 + lane], acc);
      acc = fmaf(sz[kk + 3], w[(kk + 3) * 40 + lane], acc);
    }
  }
  part[sgrp][lane] = acc;
  __syncthreads();
  if (j < 64) {
    float lv = (j < 40) ? part[0][j] + part[1][j] + part[2][j] + part[3][j] + b[j] : -INFINITY;
    float m = lv;
    for (int d = 32; d > 0; d >>= 1) m = fmaxf(m, __shfl_xor(m, d));
    float e = (j < 40) ? expf(lv - m) : 0.f;
    for (int d = 32; d > 0; d >>= 1) e += __shfl_xor(e, d);
    if (j < 40) out[bb * 40 + j] = lv - m - logf(e);
  }
}

extern "C" void kernel_launch(void* const* d_in, const int* in_sizes, int n_in,
                              void* d_out, int out_size, void* d_ws, size_t ws_size,
                              hipStream_t stream) {
  (void)in_sizes; (void)n_in; (void)out_size; (void)ws_size;
  const float* x    = (const float*)d_in[0];
  const int*   esrc = (const int*)d_in[1];
  const int*   edst = (const int*)d_in[2];
  const float* ev   = (const float*)d_in[3];
  const float* gc1w = (const float*)d_in[5];
  const float* gc1b = (const float*)d_in[6];
  const float* gc2w = (const float*)d_in[7];
  const float* gc2b = (const float*)d_in[8];
  const float* gc3w = (const float*)d_in[9];
  const float* gc3b = (const float*)d_in[10];
  const float* fc1w = (const float*)d_in[11];
  const float* fc1b = (const float*)d_in[12];
  const float* bn1g = (const float*)d_in[13];
  const float* bn1b = (const float*)d_in[14];
  const float* fc2w = (const float*)d_in[15];
  const float* fc2b = (const float*)d_in[16];
  const float* bn2g = (const float*)d_in[17];
  const float* bn2b = (const float*)d_in[18];
  const float* fc3w = (const float*)d_in[19];
  const float* fc3b = (const float*)d_in[20];

  char* ws = (char*)d_ws;
  size_t o = 0;
  auto alloc = [&](size_t bytes) -> void* {
    void* p = ws + o;
    o += (bytes + 255) & ~(size_t)255;
    return p;
  };
  int2*  offdeg = (int2*)alloc((size_t)NN * 8);
  int*   gcur = (int*)alloc(64 * 4);
  int2*  pack = (int2*)alloc((size_t)64 * PCAP * 8);
  float4* x4  = (float4*)alloc((size_t)NN * 16);
  float* bufA = (float*)alloc((size_t)NN * 64 * 4);  // ebin; later h1/h2 bf16
  float* bufB = (float*)alloc((size_t)NN * 64 * 4);  // Ahi/Alo
  uint2* ebin = (uint2*)bufA;
  unsigned short* h1_16 = (unsigned short*)bufA;
  unsigned short* h2_16 = (unsigned short*)((char*)bufA + NN * 64 * 2);
  unsigned short* Ahi = (unsigned short*)bufB;
  unsigned short* Alo = (unsigned short*)(bufB + NN * 32);
  unsigned short* Bfrag = (unsigned short*)alloc(4 * 1024 * 32 * 2);
  float* gf   = (float*)alloc(64 * 1024 * 4);
  float* z1   = (float*)alloc(64 * 512 * 4);
  float* z2   = (float*)alloc(64 * 256 * 4);

  // prep: x4 pack + gcur zero + W3 frags + gf zero
  k_prep<<<768, 256, 0, stream>>>(x, x4, gcur, gc3w, Bfrag, (unsigned*)gf);

  // CSR build: 2-pass shape-bucketed, padded to x8 per node
  k_bin<<<NE / 4096, 256, 0, stream>>>(esrc, edst, ev, gcur, ebin);
  k_csr<<<64, 1024, 0, stream>>>(gcur, ebin, offdeg, pack);

  // layer 1 fused: agg(x) @ W1 + b1, relu -> h1 bf16
  k_agg1<<<NN / 256, 256, 0, stream>>>(offdeg, pack, x4, gc1w, gc1b, h1_16);

  // layer 2 fused: agg(h1) @ W2 + b2, relu -> h2 bf16
  k_agg64g2<<<NN / 32, 256, 0, stream>>>(offdeg, pack, h1_16, gc2w, gc2b, h2_16);

  // layer 3: aggregate bf16 h2 -> split-bf16 planes, then MFMA GEMM + maxpool
  k_agg64_split<<<NN / 32, 256, 0, stream>>>(offdeg, pack, h2_16, Ahi, Alo);
  k_gemm3max<<<512, 512, 0, stream>>>(Ahi, Alo, Bfrag, gc3b, (unsigned*)gf);

  // MLP head (fc1 -> fused bn1+fc2 -> fused bn2+fc3+log_softmax)
  k_fc<<<dim3(8, 64), 512, 0, stream>>>(gf, fc1w, fc1b, z1, 1024, 512);
  k_fc2n<<<dim3(4, 64), 512, 0, stream>>>(z1, bn1g, bn1b, fc2w, fc2b, z2);
  k_head2<<<64, 256, 0, stream>>>(z2, bn2g, bn2b, fc3w, fc3b, (float*)d_out);
}

// Round 21
// 156.582 us; speedup vs baseline: 1.0281x; 1.0281x over previous
//
#include <hip/hip_runtime.h>
#include <math.h>

#define NN 65536
#define NE 1048576
#define CAP 17408   // per-bucket ebin capacity (mean 16384 + 8-sigma)
#define PCAP 24576  // per-bucket padded pack capacity

typedef __attribute__((ext_vector_type(8))) short short8;
typedef __attribute__((ext_vector_type(4))) float f32x4;

__device__ inline unsigned short f2bf(float f) {
  unsigned u = __float_as_uint(f);
  unsigned r = u + 0x7fff + ((u >> 16) & 1);  // RNE
  return (unsigned short)(r >> 16);
}
__device__ inline float bf2f(unsigned short h) { return __uint_as_float(((unsigned)h) << 16); }

// ---------------- merged prep: x packing + gcur zero + W3 split-bf16 frags + gf zero ----------
__global__ __launch_bounds__(256) void k_prep(const float* __restrict__ x, float4* __restrict__ x4,
                                              int* __restrict__ gcur, const float* __restrict__ w3,
                                              unsigned short* __restrict__ bfrag, unsigned* __restrict__ gf) {
  int bid = blockIdx.x, tid = threadIdx.x;
  if (bid < 256) {
    if (bid == 0 && tid < 64) gcur[tid] = 0;
    int n = bid * 256 + tid;
    x4[n] = make_float4(x[3 * n], x[3 * n + 1], x[3 * n + 2], 0.f);
  } else {
    int t = (bid - 256) * 256 + tid;  // 0..131071
    if (t < 65536) gf[t] = 0u;
    int e = t & 7, g = (t >> 3) & 3, col = (t >> 5) & 1023, q = t >> 15;
    int k = (q & 1) * 32 + g * 8 + e;
    float v = w3[k * 1024 + col];
    unsigned short hv = f2bf(v);
    bfrag[t] = (q < 2) ? hv : f2bf(v - bf2f(hv));
  }
}

// ---------------- CSR build, pass 1: bin edges by shape (dst>>10), vectorized reads ----------
__global__ __launch_bounds__(256) void k_bin(const int* __restrict__ src, const int* __restrict__ dst,
                                             const float* __restrict__ val, int* __restrict__ gcur,
                                             uint2* __restrict__ ebin) {
  __shared__ int cnt[64], base[64];
  int tid = threadIdx.x;
  if (tid < 64) cnt[tid] = 0;
  __syncthreads();
  int e0 = blockIdx.x * 4096;
  const int4* src4 = (const int4*)(src + e0);
  const int4* dst4 = (const int4*)(dst + e0);
  const float4* val4 = (const float4*)(val + e0);
  int rsrc[16], rdst[16], rrank[16];
  float rval[16];
#pragma unroll
  for (int i = 0; i < 4; ++i) {
    int4 s4 = src4[i * 256 + tid];
    int4 d4 = dst4[i * 256 + tid];
    float4 v4 = val4[i * 256 + tid];
    rsrc[4 * i + 0] = s4.x; rsrc[4 * i + 1] = s4.y; rsrc[4 * i + 2] = s4.z; rsrc[4 * i + 3] = s4.w;
    rdst[4 * i + 0] = d4.x; rdst[4 * i + 1] = d4.y; rdst[4 * i + 2] = d4.z; rdst[4 * i + 3] = d4.w;
    rval[4 * i + 0] = v4.x; rval[4 * i + 1] = v4.y; rval[4 * i + 2] = v4.z; rval[4 * i + 3] = v4.w;
#pragma unroll
    for (int u = 0; u < 4; ++u) rrank[4 * i + u] = atomicAdd(&cnt[rdst[4 * i + u] >> 10], 1);
  }
  __syncthreads();
  if (tid < 64) base[tid] = atomicAdd(&gcur[tid], cnt[tid]);
  __syncthreads();
#pragma unroll
  for (int i = 0; i < 16; ++i) {
    int b = rdst[i] >> 10;
    ebin[b * CAP + base[b] + rrank[i]] =
        make_uint2((unsigned)rsrc[i] | ((unsigned)(rdst[i] & 1023) << 16), (unsigned)__float_as_int(rval[i]));
  }
}

// ---------------- CSR build, pass 2: register-cached single-read, wave-shfl scan -------------
__global__ __launch_bounds__(1024) void k_csr(const int* __restrict__ gcnt, const uint2* __restrict__ ebin,
                                              int2* __restrict__ offdeg, int2* __restrict__ pack) {
  __shared__ int lcnt[1024], lcur[1024];
  __shared__ int wsum[16], woff[16];
  int b = blockIdx.x, tid = threadIdx.x;
  int count = gcnt[b];
  int gbase = b * PCAP;
  lcnt[tid] = 0;
  __syncthreads();
  const uint2* eb = ebin + (size_t)b * CAP;
  uint2 es[5][4];
#pragma unroll
  for (int i0 = 0; i0 < 5; ++i0)
#pragma unroll
    for (int u = 0; u < 4; ++u) {
      int i = i0 * 4096 + u * 1024 + tid;
      es[i0][u] = eb[min(i, count - 1)];
    }
#pragma unroll
  for (int i0 = 0; i0 < 5; ++i0)
#pragma unroll
    for (int u = 0; u < 4; ++u) {
      int i = i0 * 4096 + u * 1024 + tid;
      if (i < count) atomicAdd(&lcnt[(es[i0][u].x >> 16) & 1023], 1);
    }
  __syncthreads();
  int deg = lcnt[tid];
  int pdeg = (deg + 7) & ~7;
  int lane = tid & 63, wid = tid >> 6;
  int v = pdeg;
#pragma unroll
  for (int d = 1; d < 64; d <<= 1) {
    int t = __shfl_up(v, d);
    if (lane >= d) v += t;
  }
  if (lane == 63) wsum[wid] = v;
  __syncthreads();
  if (tid < 16) {
    int s = wsum[tid];
    int sv = s;
#pragma unroll
    for (int d = 1; d < 16; d <<= 1) {
      int t = __shfl_up(sv, d);
      if (tid >= d) sv += t;
    }
    woff[tid] = sv - s;
  }
  __syncthreads();
  int o0 = woff[wid] + v - pdeg;  // exclusive padded prefix
  lcur[tid] = o0;
  offdeg[b * 1024 + tid] = make_int2(gbase + o0, pdeg);
  __syncthreads();
#pragma unroll
  for (int i0 = 0; i0 < 5; ++i0)
#pragma unroll
    for (int u = 0; u < 4; ++u) {
      int i = i0 * 4096 + u * 1024 + tid;
      if (i < count) {
        int ld = (es[i0][u].x >> 16) & 1023;
        int p = atomicAdd(&lcur[ld], 1);
        pack[gbase + p] = make_int2((int)((es[i0][u].x & 0xffffu) << 7), (int)es[i0][u].y);
      }
    }
  int pend = o0 + pdeg;
  for (int p = o0 + deg; p < pend; ++p) pack[gbase + p] = make_int2(0, 0);
}

// ---------------- fused layer-1: agg(x) -> @W1+b1, relu -> h1 bf16 (simple 8-deep loop) ------
__global__ __launch_bounds__(256) void k_agg1(const int2* __restrict__ offdeg, const int2* __restrict__ pack,
                                              const float4* __restrict__ x4, const float* __restrict__ w,
                                              const float* __restrict__ b, unsigned short* __restrict__ out) {
  __shared__ float sw[256];
  __shared__ float sa[256][4];
  int tid = threadIdx.x;
  sw[tid] = (tid < 192) ? w[tid] : b[tid - 192];
  int n = blockIdx.x * 256 + tid;
  int2 od = offdeg[n];
  int i0 = od.x, pdeg = od.y;
  float a0 = 0.f, a1 = 0.f, a2 = 0.f;
  for (int bb = 0; bb < pdeg; bb += 8) {
    int4 p0 = *(const int4*)&pack[i0 + bb];
    int4 p1 = *(const int4*)&pack[i0 + bb + 2];
    int4 p2 = *(const int4*)&pack[i0 + bb + 4];
    int4 p3 = *(const int4*)&pack[i0 + bb + 6];
    int sx[8] = {p0.x, p0.z, p1.x, p1.z, p2.x, p2.z, p3.x, p3.z};
    int vv[8] = {p0.y, p0.w, p1.y, p1.w, p2.y, p2.w, p3.y, p3.w};
    float4 q[8];
#pragma unroll
    for (int u = 0; u < 8; ++u) q[u] = x4[(unsigned)sx[u] >> 7];
#pragma unroll
    for (int u = 0; u < 8; ++u) {
      float v = __int_as_float(vv[u]);
      a0 = fmaf(v, q[u].x, a0);
      a1 = fmaf(v, q[u].y, a1);
      a2 = fmaf(v, q[u].z, a2);
    }
  }
  sa[tid][0] = a0; sa[tid][1] = a1; sa[tid][2] = a2;
  __syncthreads();
  int j = tid & 63, g = tid >> 6;
  float wj0 = sw[j], wj1 = sw[64 + j], wj2 = sw[128 + j], bj = sw[192 + j];
  int nb = blockIdx.x * 256 + g * 64;
  for (int r = 0; r < 64; ++r) {
    float r0 = fmaf(sa[g * 64 + r][0], wj0, bj);
    r0 = fmaf(sa[g * 64 + r][1], wj1, r0);
    r0 = fmaf(sa[g * 64 + r][2], wj2, r0);
    out[(size_t)(nb + r) * 64 + j] = f2bf(fmaxf(r0, 0.f));
  }
}

// ---------------- fused layer-2: agg(h1) -> @W2+b2, relu -> h2 bf16 (simple loop) ------------
__global__ __launch_bounds__(256) void k_agg64g2(const int2* __restrict__ offdeg, const int2* __restrict__ pack,
                                                 const unsigned short* __restrict__ h,
                                                 const float* __restrict__ w2, const float* __restrict__ b2,
                                                 unsigned short* __restrict__ out) {
  __shared__ float sw[64][64];    // sw[k][j]
  __shared__ float rows[32][64];
  int tid = threadIdx.x;
  int lane = tid & 63, wv = tid >> 6;
  for (int t = tid; t < 1024; t += 256) ((float4*)sw)[t] = ((const float4*)w2)[t];
  __syncthreads();
  int o = lane >> 3, fl = lane & 7;  // node octant, feat group (feats 8fl..8fl+7)
  int n = blockIdx.x * 32 + wv * 8 + o;
  int2 od = offdeg[n];
  int i0 = od.x, pdeg = od.y;
  const char* hb = (const char*)h;
  unsigned fo = (unsigned)(fl << 4);
  float c0 = 0.f, c1 = 0.f, c2 = 0.f, c3 = 0.f, c4 = 0.f, c5 = 0.f, c6 = 0.f, c7 = 0.f;
  for (int b = 0; b < pdeg; b += 8) {
    int4 p0 = *(const int4*)&pack[i0 + b];
    int4 p1 = *(const int4*)&pack[i0 + b + 2];
    int4 p2 = *(const int4*)&pack[i0 + b + 4];
    int4 p3 = *(const int4*)&pack[i0 + b + 6];
    int sx[8] = {p0.x, p0.z, p1.x, p1.z, p2.x, p2.z, p3.x, p3.z};
    int vv[8] = {p0.y, p0.w, p1.y, p1.w, p2.y, p2.w, p3.y, p3.w};
    uint4 hv[8];
#pragma unroll
    for (int u = 0; u < 8; ++u) hv[u] = *(const uint4*)(hb + ((unsigned)sx[u] + fo));
#pragma unroll
    for (int u = 0; u < 8; ++u) {
      float v = __int_as_float(vv[u]);
      c0 = fmaf(v, __uint_as_float(hv[u].x << 16), c0);
      c1 = fmaf(v, __uint_as_float(hv[u].x & 0xffff0000u), c1);
      c2 = fmaf(v, __uint_as_float(hv[u].y << 16), c2);
      c3 = fmaf(v, __uint_as_float(hv[u].y & 0xffff0000u), c3);
      c4 = fmaf(v, __uint_as_float(hv[u].z << 16), c4);
      c5 = fmaf(v, __uint_as_float(hv[u].z & 0xffff0000u), c5);
      c6 = fmaf(v, __uint_as_float(hv[u].w << 16), c6);
      c7 = fmaf(v, __uint_as_float(hv[u].w & 0xffff0000u), c7);
    }
  }
  ((float4*)rows[wv * 8 + o])[fl * 2 + 0] = make_float4(c0, c1, c2, c3);
  ((float4*)rows[wv * 8 + o])[fl * 2 + 1] = make_float4(c4, c5, c6, c7);
  int nA = blockIdx.x * 32 + wv * 8;
  float bb = b2[lane];
  float acc[8];
#pragma unroll
  for (int r = 0; r < 8; ++r) acc[r] = bb;
#pragma unroll
  for (int kk = 0; kk < 16; ++kk) {
    float w0 = sw[4 * kk + 0][lane], w1 = sw[4 * kk + 1][lane];
    float w2v = sw[4 * kk + 2][lane], w3v = sw[4 * kk + 3][lane];
#pragma unroll
    for (int r = 0; r < 8; ++r) {
      float4 qr = ((const float4*)rows[wv * 8 + r])[kk];
      acc[r] = fmaf(qr.x, w0, acc[r]);
      acc[r] = fmaf(qr.y, w1, acc[r]);
      acc[r] = fmaf(qr.z, w2v, acc[r]);
      acc[r] = fmaf(qr.w, w3v, acc[r]);
    }
  }
#pragma unroll
  for (int r = 0; r < 8; ++r)
    out[(size_t)(nA + r) * 64 + lane] = f2bf(fmaxf(acc[r], 0.f));
}

// 64-feature aggregation -> split-bf16 planes (hi, lo); simple 8-deep loop
__global__ __launch_bounds__(256) void k_agg64_split(const int2* __restrict__ offdeg, const int2* __restrict__ pack,
                                                     const unsigned short* __restrict__ h,
                                                     unsigned short* __restrict__ hi,
                                                     unsigned short* __restrict__ lo) {
  int tid = threadIdx.x;
  int lane = tid & 63, wv = tid >> 6;
  int o = lane >> 3, fl = lane & 7;
  int n = blockIdx.x * 32 + wv * 8 + o;
  int2 od = offdeg[n];
  int i0 = od.x, pdeg = od.y;
  const char* hb = (const char*)h;
  unsigned fo = (unsigned)(fl << 4);
  float c0 = 0.f, c1 = 0.f, c2 = 0.f, c3 = 0.f, c4 = 0.f, c5 = 0.f, c6 = 0.f, c7 = 0.f;
  for (int b = 0; b < pdeg; b += 8) {
    int4 p0 = *(const int4*)&pack[i0 + b];
    int4 p1 = *(const int4*)&pack[i0 + b + 2];
    int4 p2 = *(const int4*)&pack[i0 + b + 4];
    int4 p3 = *(const int4*)&pack[i0 + b + 6];
    int sx[8] = {p0.x, p0.z, p1.x, p1.z, p2.x, p2.z, p3.x, p3.z};
    int vv[8] = {p0.y, p0.w, p1.y, p1.w, p2.y, p2.w, p3.y, p3.w};
    uint4 hv[8];
#pragma unroll
    for (int u = 0; u < 8; ++u) hv[u] = *(const uint4*)(hb + ((unsigned)sx[u] + fo));
#pragma unroll
    for (int u = 0; u < 8; ++u) {
      float v = __int_as_float(vv[u]);
      c0 = fmaf(v, __uint_as_float(hv[u].x << 16), c0);
      c1 = fmaf(v, __uint_as_float(hv[u].x & 0xffff0000u), c1);
      c2 = fmaf(v, __uint_as_float(hv[u].y << 16), c2);
      c3 = fmaf(v, __uint_as_float(hv[u].y & 0xffff0000u), c3);
      c4 = fmaf(v, __uint_as_float(hv[u].z << 16), c4);
      c5 = fmaf(v, __uint_as_float(hv[u].z & 0xffff0000u), c5);
      c6 = fmaf(v, __uint_as_float(hv[u].w << 16), c6);
      c7 = fmaf(v, __uint_as_float(hv[u].w & 0xffff0000u), c7);
    }
  }
  unsigned short h0 = f2bf(c0), h1 = f2bf(c1), h2 = f2bf(c2), h3 = f2bf(c3);
  unsigned short h4 = f2bf(c4), h5 = f2bf(c5), h6 = f2bf(c6), h7 = f2bf(c7);
  uint4 hiw = make_uint4((unsigned)h0 | ((unsigned)h1 << 16), (unsigned)h2 | ((unsigned)h3 << 16),
                         (unsigned)h4 | ((unsigned)h5 << 16), (unsigned)h6 | ((unsigned)h7 << 16));
  unsigned short l0 = f2bf(c0 - bf2f(h0)), l1 = f2bf(c1 - bf2f(h1));
  unsigned short l2 = f2bf(c2 - bf2f(h2)), l3 = f2bf(c3 - bf2f(h3));
  unsigned short l4 = f2bf(c4 - bf2f(h4)), l5 = f2bf(c5 - bf2f(h5));
  unsigned short l6 = f2bf(c6 - bf2f(h6)), l7 = f2bf(c7 - bf2f(h7));
  uint4 low = make_uint4((unsigned)l0 | ((unsigned)l1 << 16), (unsigned)l2 | ((unsigned)l3 << 16),
                         (unsigned)l4 | ((unsigned)l5 << 16), (unsigned)l6 | ((unsigned)l7 << 16));
  ((uint4*)hi)[(size_t)n * 8 + fl] = hiw;
  ((uint4*)lo)[(size_t)n * 8 + fl] = low;
}

// ---------------- GCN layer 3 GEMM + maxpool via MFMA (split-bf16 A and W) -------------------
__global__ __launch_bounds__(512) void k_gemm3max(const unsigned short* __restrict__ Ahi,
                                                  const unsigned short* __restrict__ Alo,
                                                  const unsigned short* __restrict__ Bfrag,
                                                  const float* __restrict__ b3,
                                                  unsigned* __restrict__ gf) {
  int b = blockIdx.x;
  int colhalf = b & 1, rowchunk = b >> 1;
  int shape = rowchunk >> 2;
  int tid = threadIdx.x;
  int wv = tid >> 6, l = tid & 63;
  int g = l >> 4, lr = l & 15;

  const short8* bf = (const short8*)Bfrag;
  int c0 = colhalf * 512 + wv * 64 + lr;
  short8 B0[4], B1[4], B2[4], B3[4];
#pragma unroll
  for (int ct = 0; ct < 4; ++ct) {
    int col = c0 + ct * 16;
    B0[ct] = bf[(0 * 1024 + col) * 4 + g];
    B1[ct] = bf[(1 * 1024 + col) * 4 + g];
    B2[ct] = bf[(2 * 1024 + col) * 4 + g];
    B3[ct] = bf[(3 * 1024 + col) * 4 + g];
  }

  float m[4] = {-1e30f, -1e30f, -1e30f, -1e30f};
  size_t abase = ((size_t)rowchunk * 256 + lr) * 64 + g * 8;
  for (int t = 0; t < 16; ++t) {
    size_t o = abase + (size_t)t * 16 * 64;
    short8 ah0 = *(const short8*)(Ahi + o);
    short8 ah1 = *(const short8*)(Ahi + o + 32);
    short8 al0 = *(const short8*)(Alo + o);
    short8 al1 = *(const short8*)(Alo + o + 32);
#pragma unroll
    for (int ct = 0; ct < 4; ++ct) {
      f32x4 acc = {0.f, 0.f, 0.f, 0.f};
      acc = __builtin_amdgcn_mfma_f32_16x16x32_bf16(ah0, B0[ct], acc, 0, 0, 0);
      acc = __builtin_amdgcn_mfma_f32_16x16x32_bf16(ah1, B1[ct], acc, 0, 0, 0);
      acc = __builtin_amdgcn_mfma_f32_16x16x32_bf16(ah0, B2[ct], acc, 0, 0, 0);
      acc = __builtin_amdgcn_mfma_f32_16x16x32_bf16(ah1, B3[ct], acc, 0, 0, 0);
      acc = __builtin_amdgcn_mfma_f32_16x16x32_bf16(al0, B0[ct], acc, 0, 0, 0);
      acc = __builtin_amdgcn_mfma_f32_16x16x32_bf16(al1, B1[ct], acc, 0, 0, 0);
      m[ct] = fmaxf(m[ct], fmaxf(fmaxf(acc[0], acc[1]), fmaxf(acc[2], acc[3])));
    }
  }
#pragma unroll
  for (int ct = 0; ct < 4; ++ct) {
    float mm = m[ct];
    mm = fmaxf(mm, __shfl_xor(mm, 16));
    mm = fmaxf(mm, __shfl_xor(mm, 32));
    if (g == 0) {
      int col = c0 + ct * 16;
      float v = fmaxf(mm + b3[col], 0.f);
      atomicMax(&gf[shape * 1024 + col], __float_as_uint(v));
    }
  }
}

// ---------------- MLP head ----------------
__global__ __launch_bounds__(512) void k_fc(const float* __restrict__ in, const float* __restrict__ w,
                                            const float* __restrict__ bias, float* __restrict__ out,
                                            int K, int J) {
  __shared__ float sin_[1024];
  __shared__ float part[8][64];
  int jt = blockIdx.x, bb = blockIdx.y;
  int tid = threadIdx.x, s = tid >> 6, lane = tid & 63;
  for (int i = tid; i < K; i += 512) sin_[i] = in[bb * K + i];
  __syncthreads();
  int j = (jt << 6) + lane;
  int Ks = K >> 3;
  int k0 = s * Ks;
  float acc = 0.f;
  for (int k = 0; k < Ks; k += 16) {
    float wv[16];
#pragma unroll
    for (int u = 0; u < 16; ++u) wv[u] = w[(k0 + k + u) * J + j];
#pragma unroll
    for (int u = 0; u < 16; ++u) acc = fmaf(sin_[k0 + k + u], wv[u], acc);
  }
  part[s][lane] = acc;
  __syncthreads();
  if (tid < 64) {
    float r = bias[(jt << 6) + tid];
#pragma unroll
    for (int u = 0; u < 8; ++u) r += part[u][tid];
    out[bb * J + (jt << 6) + tid] = r;
  }
}

// fused BN1 + relu + fc2: grid (4, 64) = (jt, row)
__global__ __launch_bounds__(512) void k_fc2n(const float* __restrict__ z1, const float* __restrict__ g1,
                                              const float* __restrict__ be1, const float* __restrict__ w,
                                              const float* __restrict__ bias, float* __restrict__ out) {
  __shared__ float szn[512];
  __shared__ float part[8][64];
  int jt = blockIdx.x, row = blockIdx.y;
  int tid = threadIdx.x;
  {
    float s = 0.f;
#pragma unroll 8
    for (int r = 0; r < 64; ++r) s += z1[r * 512 + tid];
    float mean = s * (1.f / 64.f);
    float v = 0.f;
#pragma unroll 8
    for (int r = 0; r < 64; ++r) {
      float d = z1[r * 512 + tid] - mean;
      v = fmaf(d, d, v);
    }
    float scale = g1[tid] / sqrtf(v * (1.f / 64.f) + 1e-5f);
    float shift = be1[tid] - mean * scale;
    szn[tid] = fmaxf(fmaf(z1[row * 512 + tid], scale, shift), 0.f);
  }
  __syncthreads();
  int s8 = tid >> 6, lane = tid & 63;
  int j = (jt << 6) + lane;
  int k0 = s8 * 64;
  float acc = 0.f;
  for (int k = 0; k < 64; k += 16) {
    float wv[16];
#pragma unroll
    for (int u = 0; u < 16; ++u) wv[u] = w[(k0 + k + u) * 256 + j];
#pragma unroll
    for (int u = 0; u < 16; ++u) acc = fmaf(szn[k0 + k + u], wv[u], acc);
  }
  part[s8][lane] = acc;
  __syncthreads();
  if (tid < 64) {
    float r = bias[(jt << 6) + tid];
#pragma unroll
    for (int u = 0; u < 8; ++u) r += part[u][tid];
    out[row * 256 + (jt << 6) + tid] = r;
  }
}

// fused BN2 + relu + fc3 + log_softmax: grid 64 (one block per batch row)
__global__ __launch_bounds__(256) void k_head2(const float* __restrict__ z2, const float* __restrict__ g,
                                               const float* __restrict__ bt, const float* __restrict__ w,
                                               const float* __restrict__ b, float* __restrict__ out) {
  __shared__ float sz[256];
  __shared__ float part[4][64];
  int bb = blockIdx.x, j = threadIdx.x;
  float s = 0.f;
#pragma unroll 8
  for (int r = 0; r < 64; ++r) s += z2[r * 256 + j];
  float mean = s * (1.f / 64.f);
  float v = 0.f;
#pragma unroll 8
  for (int r = 0; r < 64; ++r) {
    float d = z2[r * 256 + j] - mean;
    v = fmaf(d, d, v);
  }
  float scale = g[j] / sqrtf(v * (1.f / 64.f) + 1e-5f);
  float shift = bt[j] - mean * scale;
  sz[j] = fmaxf(fmaf(z2[bb * 256 + j], scale, shift), 0.f);
  __syncthreads();
  int sgrp = j >> 6, lane = j & 63;
  float acc = 0.f;
  if (lane < 40) {
#pragma unroll
    for (int k = 0; k < 64; k += 4) {
      int kk = sgrp * 64 + k;
      acc = fmaf(sz[kk + 0], w[(kk + 0) * 40 + lane], acc);
      acc = fmaf(sz[kk + 1], w[(kk + 1) * 40 + lane], acc);
      acc = fmaf(sz[kk + 2], w[(kk + 2) * 40 + lane], acc);
      acc = fmaf(sz[kk + 3], w[(kk + 3) * 40 + lane], acc);
    }
  }
  part[sgrp][lane] = acc;
  __syncthreads();
  if (j < 64) {
    float lv = (j < 40) ? part[0][j] + part[1][j] + part[2][j] + part[3][j] + b[j] : -INFINITY;
    float m = lv;
    for (int d = 32; d > 0; d >>= 1) m = fmaxf(m, __shfl_xor(m, d));
    float e = (j < 40) ? expf(lv - m) : 0.f;
    for (int d = 32; d > 0; d >>= 1) e += __shfl_xor(e, d);
    if (j < 40) out[bb * 40 + j] = lv - m - logf(e);
  }
}

extern "C" void kernel_launch(void* const* d_in, const int* in_sizes, int n_in,
                              void* d_out, int out_size, void* d_ws, size_t ws_size,
                              hipStream_t stream) {
  (void)in_sizes; (void)n_in; (void)out_size; (void)ws_size;
  const float* x    = (const float*)d_in[0];
  const int*   esrc = (const int*)d_in[1];
  const int*   edst = (const int*)d_in[2];
  const float* ev   = (const float*)d_in[3];
  const float* gc1w = (const float*)d_in[5];
  const float* gc1b = (const float*)d_in[6];
  const float* gc2w = (const float*)d_in[7];
  const float* gc2b = (const float*)d_in[8];
  const float* gc3w = (const float*)d_in[9];
  const float* gc3b = (const float*)d_in[10];
  const float* fc1w = (const float*)d_in[11];
  const float* fc1b = (const float*)d_in[12];
  const float* bn1g = (const float*)d_in[13];
  const float* bn1b = (const float*)d_in[14];
  const float* fc2w = (const float*)d_in[15];
  const float* fc2b = (const float*)d_in[16];
  const float* bn2g = (const float*)d_in[17];
  const float* bn2b = (const float*)d_in[18];
  const float* fc3w = (const float*)d_in[19];
  const float* fc3b = (const float*)d_in[20];

  char* ws = (char*)d_ws;
  size_t o = 0;
  auto alloc = [&](size_t bytes) -> void* {
    void* p = ws + o;
    o += (bytes + 255) & ~(size_t)255;
    return p;
  };
  int2*  offdeg = (int2*)alloc((size_t)NN * 8);
  int*   gcur = (int*)alloc(64 * 4);
  int2*  pack = (int2*)alloc((size_t)64 * PCAP * 8);
  float4* x4  = (float4*)alloc((size_t)NN * 16);
  float* bufA = (float*)alloc((size_t)NN * 64 * 4);  // ebin; later h1/h2 bf16
  float* bufB = (float*)alloc((size_t)NN * 64 * 4);  // Ahi/Alo
  uint2* ebin = (uint2*)bufA;
  unsigned short* h1_16 = (unsigned short*)bufA;
  unsigned short* h2_16 = (unsigned short*)((char*)bufA + NN * 64 * 2);
  unsigned short* Ahi = (unsigned short*)bufB;              // 8 MB
  unsigned short* Alo = (unsigned short*)(bufB + NN * 32);  // 8 MB
  unsigned short* Bfrag = (unsigned short*)alloc(4 * 1024 * 32 * 2);
  float* gf   = (float*)alloc(64 * 1024 * 4);
  float* z1   = (float*)alloc(64 * 512 * 4);
  float* z2   = (float*)alloc(64 * 256 * 4);

  // prep: x4 pack + gcur zero + W3 frags + gf zero
  k_prep<<<768, 256, 0, stream>>>(x, x4, gcur, gc3w, Bfrag, (unsigned*)gf);

  // CSR build: 2-pass shape-bucketed, padded to x8 per node
  k_bin<<<NE / 4096, 256, 0, stream>>>(esrc, edst, ev, gcur, ebin);
  k_csr<<<64, 1024, 0, stream>>>(gcur, ebin, offdeg, pack);

  // layer 1 fused: agg(x) @ W1 + b1, relu -> h1 bf16
  k_agg1<<<NN / 256, 256, 0, stream>>>(offdeg, pack, x4, gc1w, gc1b, h1_16);

  // layer 2 fused: agg(h1) @ W2 + b2, relu -> h2 bf16
  k_agg64g2<<<NN / 32, 256, 0, stream>>>(offdeg, pack, h1_16, gc2w, gc2b, h2_16);

  // layer 3: aggregate bf16 h2 -> split-bf16 planes, then MFMA GEMM + maxpool
  k_agg64_split<<<NN / 32, 256, 0, stream>>>(offdeg, pack, h2_16, Ahi, Alo);
  k_gemm3max<<<512, 512, 0, stream>>>(Ahi, Alo, Bfrag, gc3b, (unsigned*)gf);

  // MLP head (fc1 -> fused bn1+fc2 -> fused bn2+fc3+log_softmax)
  k_fc<<<dim3(8, 64), 512, 0, stream>>>(gf, fc1w, fc1b, z1, 1024, 512);
  k_fc2n<<<dim3(4, 64), 512, 0, stream>>>(z1, bn1g, bn1b, fc2w, fc2b, z2);
  k_head2<<<64, 256, 0, stream>>>(z2, bn2g, bn2b, fc3w, fc3b, (float*)d_out);
}